// Round 30
// baseline (6001.538 us; speedup 1.0000x reference)
//
#include <hip/hip_runtime.h>

#define BETA_F 0.9048374180359595f   // fp32 nearest of exp(-0.1)

constexpr int B_ = 16, C1_ = 16, C2_ = 16;
constexpr int S1 = 60, S2 = 56;
constexpr int NCONV2 = C2_ * S2 * S2;   // 50176
constexpr int NREC = 256;

// ---- persistent state (t-parity double buffers) ----
__device__ float g_mem_c1x[2 * 921600];
__device__ float g_mem_c2[802816];
__device__ float g_mem_rec[4096];
__device__ float g_mem_d2[921600];
__device__ float g_mem_rc[65536];
__device__ unsigned char g_spkpx[2][NCONV2 * 16];   // packed [k][b] spikes
__device__ float g_currx[2][B_ * NCONV2];
__device__ float g_spkd2x[2][921600];
__device__ float g_spkrec2[2 * 4096];
__device__ float g_woutT[NREC * NCONV2];

// LIF subtract-reset, fp32, unfused mul-then-add (order frozen since r13)
__device__ __forceinline__ float lif_sub(float mp, float inp, float& mn_out) {
    float rst = mp > 1.f ? 1.f : 0.f;
    float base = __fadd_rn(__fmul_rn(BETA_F, mp), inp);
    float mn = __fsub_rn(base, rst);
    mn_out = mn;
    return mn > 1.f ? 1.f : 0.f;
}

// ---------------- Wout transpose (bit-copy; once per launch) ----------------
__global__ void k_transpose(const float* __restrict__ Wout) {
    __shared__ float T[64][65];
    int m0 = blockIdx.x * 64;
    for (int k0 = 0; k0 < 256; k0 += 64) {
        __syncthreads();
        for (int e = threadIdx.x; e < 64 * 64; e += 256) {
            int i = e >> 6, k = e & 63;
            T[i][k] = Wout[(size_t)(m0 + i) * 256 + k0 + k];
        }
        __syncthreads();
        for (int e = threadIdx.x; e < 64 * 64; e += 256) {
            int k = e >> 6, i = e & 63;
            g_woutT[(size_t)(k0 + k) * NCONV2 + m0 + i] = T[i][k];
        }
    }
}

// =============== wavefront kernel: 5 layer-instances, disjoint block ranges ==
// [0,448): conv12@k | [448,1472): ffinrec@k-1 | [1472,1864): ffout@k-2
// [1864,2344): deconv2@k-3 | [2344,2856): recon@k-4
__global__ __launch_bounds__(256)
void k_wave(int kw,
            const float* __restrict__ x, const float* __restrict__ osc,
            const float* __restrict__ w1, const float* __restrict__ b1,
            const float* __restrict__ w2, const float* __restrict__ b2,
            const float* __restrict__ win, const float* __restrict__ bin,
            const float* __restrict__ wrec, const float* __restrict__ brec,
            const float* __restrict__ bout,
            const float* __restrict__ wd2, const float* __restrict__ bd2,
            const float* __restrict__ wrc, const float* __restrict__ brc,
            float* __restrict__ out_recs, float* __restrict__ out_outs) {
    __shared__ float smem[8192];           // 32768 B union -> 5 blocks/CU
    const int r = blockIdx.x;
    const int tid = threadIdx.x;

    if (r < 448) {
        // ---------------- A: conv12 @ t = kw (4-row tiles; x from global) ----
        int t = kw;
        if (t > 49) return;
        int first = (t == 0) ? 1 : 0;
        float* s1 = smem;                  // 16*8*60 = 7680
        int tile = r % 14, b = (r / 14) & 15, half = r / 224;
        int y0 = 4 * tile;                 // window rows [y0, y0+8)
        int y1 = (tile == 13) ? 60 : (y0 + 4);
        const float* xin = x + ((size_t)t * B_ + b) * 4096;

        int par = t & 1;
        float* mc1_new = g_mem_c1x + (size_t)par * 921600;
        const float* mc1_old = g_mem_c1x + (size_t)(1 - par) * 921600;
        unsigned char* spkp = g_spkpx[par];
        float osct = osc[t];
#pragma unroll 1
        for (int c = 0; c < 16; c++) {
            const float* wc = w1 + c * 25;
            float bc = b1[c];
            for (int e = tid; e < 8 * 60; e += 256) {
                int rr = e / 60, col = e % 60;
                float s = 0.f;
#pragma unroll
                for (int ky = 0; ky < 5; ky++)
#pragma unroll
                    for (int kx = 0; kx < 5; kx++)
                        s = fmaf(xin[(y0 + rr + ky) * 64 + col + kx], wc[ky * 5 + kx], s);
                float inp = __fadd_rn(__fadd_rn(s, bc), osct);
                int gr = y0 + rr;
                int gidx = ((b * 16 + c) * 60 + gr) * 60 + col;
                float mp = first ? 0.f : mc1_old[gidx];
                float mn;
                float spk = lif_sub(mp, inp, mn);
                if (half == 0 && gr < y1) mc1_new[gidx] = mn;
                s1[c * 480 + e] = spk;
            }
        }
        __syncthreads();

        if (tid >= 224) return;
        int p = tile * 224 + tid;          // 14*224 = 3136
        int yy = p / 56, xx = p % 56;
        int c2lo = half * 8;
        float acc[8];
#pragma unroll
        for (int u = 0; u < 8; u++) acc[u] = 0.f;
#pragma unroll 1
        for (int ci = 0; ci < 16; ci++) {
            const float* ip = s1 + ci * 480 + (yy - y0) * 60 + xx;
            float ipv[25];
#pragma unroll
            for (int ky = 0; ky < 5; ky++)
#pragma unroll
                for (int kx = 0; kx < 5; kx++)
                    ipv[ky * 5 + kx] = ip[ky * 60 + kx];
#pragma unroll
            for (int u = 0; u < 8; u++) {
                const float* wp = w2 + (c2lo + u) * 400 + ci * 25;
                float s = acc[u];
#pragma unroll
                for (int k = 0; k < 25; k++)
                    s = fmaf(ipv[k], wp[k], s);
                acc[u] = s;
            }
        }
#pragma unroll 1
        for (int u = 0; u < 8; u++) {
            int c2 = c2lo + u;
            float inp = __fadd_rn(__fadd_rn(acc[u], b2[c2]), osct);
            int idx = (b * 16 + c2) * 3136 + p;
            float mp = first ? 0.f : g_mem_c2[idx];
            float mn;
            float spk = lif_sub(mp, inp, mn);
            g_mem_c2[idx] = mn;
            spkp[(size_t)(c2 * 3136 + p) * 16 + b] = (unsigned char)(spk > 0.5f ? 1 : 0);
        }
    } else if (r < 1472) {
        // ---------------- B: ffinrec @ t = kw-1 (packed spikes, 2x unroll) ----
        int t = kw - 1;
        if (t < 0 || t > 49) return;
        int first = (t == 0) ? 1 : 0;
        float* red = smem;                 // 256
        float* sprev = smem + 256;         // 1024
        float* cur = smem + 1280;          // 4
        int bid = r - 448;
        int n = ((bid >> 5) << 3) + (bid & 7);
        int bg = ((bid >> 3) & 3) * 4;
        int par = t & 1;
        const float* sp_old = g_spkrec2 + (size_t)(1 - par) * 4096;
#pragma unroll
        for (int l = 0; l < 4; l++) {
            int e = tid + l * 256;
            sprev[e] = first ? 0.f : sp_old[(bg + (e >> 8)) * 256 + (e & 255)];
        }
        const unsigned char* spb = g_spkpx[par] + bg;   // +b offset within [k][16]
        const float* wrow = win + (size_t)n * NCONV2;
        float a0 = 0.f, a1 = 0.f, a2 = 0.f, a3 = 0.f;
        // 49 j-iters = 24x2 + 1; per-accumulator FMA order strictly k-ascending
#pragma unroll 1
        for (int jj = 0; jj < 24; jj++) {
            int k = tid + (2 * jj) * 1024;
            int k2 = k + 1024;
            float w0 = wrow[k];
            float wA = wrow[k + 256];
            float wB = wrow[k + 512];
            float wC = wrow[k + 768];
            float v0 = wrow[k2];
            float vA = wrow[k2 + 256];
            float vB = wrow[k2 + 512];
            float vC = wrow[k2 + 768];
            uchar4 q0 = *reinterpret_cast<const uchar4*>(spb + (size_t)k * 16);
            uchar4 q1 = *reinterpret_cast<const uchar4*>(spb + (size_t)(k + 256) * 16);
            uchar4 q2 = *reinterpret_cast<const uchar4*>(spb + (size_t)(k + 512) * 16);
            uchar4 q3 = *reinterpret_cast<const uchar4*>(spb + (size_t)(k + 768) * 16);
            uchar4 r0 = *reinterpret_cast<const uchar4*>(spb + (size_t)k2 * 16);
            uchar4 r1 = *reinterpret_cast<const uchar4*>(spb + (size_t)(k2 + 256) * 16);
            uchar4 r2 = *reinterpret_cast<const uchar4*>(spb + (size_t)(k2 + 512) * 16);
            uchar4 r3 = *reinterpret_cast<const uchar4*>(spb + (size_t)(k2 + 768) * 16);
            a0 = fmaf((float)q0.x, w0, a0); a1 = fmaf((float)q0.y, w0, a1);
            a2 = fmaf((float)q0.z, w0, a2); a3 = fmaf((float)q0.w, w0, a3);
            a0 = fmaf((float)q1.x, wA, a0); a1 = fmaf((float)q1.y, wA, a1);
            a2 = fmaf((float)q1.z, wA, a2); a3 = fmaf((float)q1.w, wA, a3);
            a0 = fmaf((float)q2.x, wB, a0); a1 = fmaf((float)q2.y, wB, a1);
            a2 = fmaf((float)q2.z, wB, a2); a3 = fmaf((float)q2.w, wB, a3);
            a0 = fmaf((float)q3.x, wC, a0); a1 = fmaf((float)q3.y, wC, a1);
            a2 = fmaf((float)q3.z, wC, a2); a3 = fmaf((float)q3.w, wC, a3);
            a0 = fmaf((float)r0.x, v0, a0); a1 = fmaf((float)r0.y, v0, a1);
            a2 = fmaf((float)r0.z, v0, a2); a3 = fmaf((float)r0.w, v0, a3);
            a0 = fmaf((float)r1.x, vA, a0); a1 = fmaf((float)r1.y, vA, a1);
            a2 = fmaf((float)r1.z, vA, a2); a3 = fmaf((float)r1.w, vA, a3);
            a0 = fmaf((float)r2.x, vB, a0); a1 = fmaf((float)r2.y, vB, a1);
            a2 = fmaf((float)r2.z, vB, a2); a3 = fmaf((float)r2.w, vB, a3);
            a0 = fmaf((float)r3.x, vC, a0); a1 = fmaf((float)r3.y, vC, a1);
            a2 = fmaf((float)r3.z, vC, a2); a3 = fmaf((float)r3.w, vC, a3);
        }
        {   // tail j = 48
            int k = tid + 48 * 1024;
            float w0 = wrow[k];
            float wA = wrow[k + 256];
            float wB = wrow[k + 512];
            float wC = wrow[k + 768];
            uchar4 q0 = *reinterpret_cast<const uchar4*>(spb + (size_t)k * 16);
            uchar4 q1 = *reinterpret_cast<const uchar4*>(spb + (size_t)(k + 256) * 16);
            uchar4 q2 = *reinterpret_cast<const uchar4*>(spb + (size_t)(k + 512) * 16);
            uchar4 q3 = *reinterpret_cast<const uchar4*>(spb + (size_t)(k + 768) * 16);
            a0 = fmaf((float)q0.x, w0, a0); a1 = fmaf((float)q0.y, w0, a1);
            a2 = fmaf((float)q0.z, w0, a2); a3 = fmaf((float)q0.w, w0, a3);
            a0 = fmaf((float)q1.x, wA, a0); a1 = fmaf((float)q1.y, wA, a1);
            a2 = fmaf((float)q1.z, wA, a2); a3 = fmaf((float)q1.w, wA, a3);
            a0 = fmaf((float)q2.x, wB, a0); a1 = fmaf((float)q2.y, wB, a1);
            a2 = fmaf((float)q2.z, wB, a2); a3 = fmaf((float)q2.w, wB, a3);
            a0 = fmaf((float)q3.x, wC, a0); a1 = fmaf((float)q3.y, wC, a1);
            a2 = fmaf((float)q3.z, wC, a2); a3 = fmaf((float)q3.w, wC, a3);
        }
        float accs[4] = {a0, a1, a2, a3};
#pragma unroll
        for (int u = 0; u < 4; u++) {
            red[tid] = accs[u];
            __syncthreads();
            for (int st = 128; st > 0; st >>= 1) {   // frozen tree
                if (tid < st) red[tid] = __fadd_rn(red[tid], red[tid + st]);
                __syncthreads();
            }
            if (tid == 0) cur[u] = red[0];
            __syncthreads();
        }
        if (tid < 4) {
            int bb = bg + tid;
            const float* wr = wrec + (size_t)n * 256;
            float acc = 0.f;
            for (int k = 0; k < 256; k++) acc = fmaf(sprev[tid * 256 + k], wr[k], acc);
            float cin = __fadd_rn(cur[tid], bin[n]);
            float crc = __fadd_rn(acc, brec[n]);
            float inp = __fadd_rn(__fadd_rn(cin, crc), osc[t]);
            int idx = bb * 256 + n;
            float mp = first ? 0.f : g_mem_rec[idx];
            float rst = mp > 1.f ? 1.f : 0.f;
            float base = __fadd_rn(__fmul_rn(BETA_F, mp), inp);
            float mn = (rst > 0.f) ? 0.f : base;
            g_mem_rec[idx] = mn;
            float spk = mn > 1.f ? 1.f : 0.f;
            g_spkrec2[(size_t)par * 4096 + idx] = spk;
            out_recs[(size_t)t * 4096 + idx] = spk;
        }
    } else if (r < 1864) {
        // ---------------- C: ffout @ t = kw-2 ----------------
        int t = kw - 2;
        if (t < 0 || t > 49) return;
        float* S = smem;                   // [8][256]
        int r2 = r - 1472;
        int mblk = r2 % 196;
        int bhalf = (r2 / 196) * 8;
        int par = t & 1;
#pragma unroll
        for (int l = 0; l < 8; l++) {
            int e = tid + l * 256;
            S[(e >> 8) * 256 + (e & 255)] =
                g_spkrec2[(size_t)par * 4096 + (bhalf + (e >> 8)) * 256 + (e & 255)];
        }
        __syncthreads();
        int m = mblk * 256 + tid;
        float* currw = g_currx[par];
        float acc[8];
#pragma unroll
        for (int b = 0; b < 8; b++) acc[b] = 0.f;
#pragma unroll 4
        for (int k = 0; k < 256; k++) {    // frozen k order per output
            float w = g_woutT[(size_t)k * NCONV2 + m];
#pragma unroll
            for (int b = 0; b < 8; b++) acc[b] = fmaf(S[b * 256 + k], w, acc[b]);
        }
        float bb = bout[m];
#pragma unroll
        for (int b = 0; b < 8; b++)
            currw[(size_t)(bhalf + b) * NCONV2 + m] = __fadd_rn(acc[b], bb);
    } else if (r < 2344) {
        // ---------------- D: deconv2 @ t = kw-3 (4-row tiles) ----------------
        int t = kw - 3;
        if (t < 0 || t > 49) return;
        int first = (t == 0) ? 1 : 0;
        float* sd = smem;                  // 16*8*64 = 8192
        int r3 = r - 1864;
        int tile = r3 % 15, b = (r3 / 15) & 15, half = r3 / 240;
        int r0 = 4 * tile;                 // output rows [r0, r0+4)
        int y0p = r0 - 4;
        int par = t & 1;
        const float* in = g_currx[par] + (size_t)b * NCONV2;
        for (int e = tid; e < 16 * 8 * 64; e += 256) {
            int ci = e / 512;
            int rem = e - ci * 512;
            int rr = rem >> 6, j = rem & 63;
            int iy = y0p + rr;
            int ix = j - 4;
            float v = (iy >= 0 && iy < 56 && ix >= 0 && ix < 56)
                        ? in[ci * 3136 + iy * 56 + ix] : 0.f;
            sd[e] = v;
        }
        __syncthreads();
        if (tid >= 240) return;
        int p = r0 * 60 + tid;             // 4 rows x 60
        int yy = p / 60, xx = p % 60;
        int colo = half * 8;
        float acc[8];
#pragma unroll
        for (int u = 0; u < 8; u++) acc[u] = 0.f;
#pragma unroll
        for (int kp = 0; kp < 5; kp++) {
            int rr = yy - r0 + kp;
#pragma unroll 1
            for (int ci = 0; ci < 16; ci++) {
                const float* ip = sd + ci * 512 + rr * 64 + xx;
                float ipv[5];
#pragma unroll
                for (int kq = 0; kq < 5; kq++) ipv[kq] = ip[kq];
#pragma unroll
                for (int u = 0; u < 8; u++) {
                    const float* wp = wd2 + (ci * 16 + colo + u) * 25 + (4 - kp) * 5;
                    float s = acc[u];
#pragma unroll
                    for (int kq = 0; kq < 5; kq++)
                        s = fmaf(ipv[kq], wp[4 - kq], s);
                    acc[u] = s;
                }
            }
        }
        float osct = osc[t];
        float* spkd2w = g_spkd2x[par];
#pragma unroll 1
        for (int u = 0; u < 8; u++) {
            int co = colo + u;
            float inp = __fadd_rn(__fadd_rn(acc[u], bd2[co]), osct);
            int idx = (b * 16 + co) * 3600 + p;
            float mp = first ? 0.f : g_mem_d2[idx];
            float mn;
            float spk = lif_sub(mp, inp, mn);
            g_mem_d2[idx] = mn;
            spkd2w[idx] = spk;
        }
    } else {
        // ---------------- E: recon @ t = kw-4 (2-row tiles) ----------------
        int t = kw - 4;
        if (t < 0 || t > 49) return;
        int first = (t == 0) ? 1 : 0;
        float* sd = smem;                  // 16*6*68 = 6528
        int r4 = r - 2344;
        int tile = r4 & 31, b = r4 >> 5;
        int yymin = tile * 2;
        int y0p = yymin - 4;
        int par = t & 1;
        const float* in = g_spkd2x[par] + (size_t)b * 16 * 3600;
        for (int e = tid; e < 16 * 6 * 68; e += 256) {
            int ci = e / 408;
            int rem = e - ci * 408;
            int rr = rem / 68, j = rem - rr * 68;
            int iy = y0p + rr;
            int ix = j - 4;
            float v = (iy >= 0 && iy < 60 && ix >= 0 && ix < 60)
                        ? in[ci * 3600 + iy * 60 + ix] : 0.f;
            sd[e] = v;
        }
        __syncthreads();
        if (tid >= 128) return;
        int p = yymin * 64 + tid;          // 2 rows x 64
        int yy = p >> 6, xx = p & 63;
        float s = 0.f;
#pragma unroll
        for (int kp = 0; kp < 5; kp++) {
            int rr = yy - yymin + kp;
#pragma unroll 1
            for (int ci = 0; ci < 16; ci++) {
                const float* ip = sd + ci * 408 + rr * 68 + xx;
                const float* wp = wrc + ci * 25 + (4 - kp) * 5;   // uniform -> s_load
#pragma unroll
                for (int kq = 0; kq < 5; kq++)
                    s = fmaf(ip[kq], wp[4 - kq], s);
            }
        }
        float inp = __fadd_rn(__fadd_rn(s, brc[0]), osc[t]);
        int idx = b * 4096 + p;
        float mp = first ? 0.f : g_mem_rc[idx];
        float mn;
        float spk = lif_sub(mp, inp, mn);
        g_mem_rc[idx] = mn;
        out_outs[(size_t)t * B_ * 4096 + idx] = spk;
    }
}

extern "C" void kernel_launch(void* const* d_in, const int* in_sizes, int n_in,
                              void* d_out, int out_size, void* d_ws, size_t ws_size,
                              hipStream_t stream) {
    const float* x    = (const float*)d_in[0];
    const float* osc  = (const float*)d_in[1];
    const float* w1   = (const float*)d_in[2];
    const float* b1   = (const float*)d_in[3];
    const float* w2   = (const float*)d_in[4];
    const float* b2   = (const float*)d_in[5];
    const float* win  = (const float*)d_in[6];
    const float* bin  = (const float*)d_in[7];
    const float* wrec = (const float*)d_in[8];
    const float* brec = (const float*)d_in[9];
    const float* wout = (const float*)d_in[10];
    const float* bout = (const float*)d_in[11];
    const float* wd2  = (const float*)d_in[12];
    const float* bd2  = (const float*)d_in[13];
    const float* wrc  = (const float*)d_in[14];
    const float* brc  = (const float*)d_in[15];

    float* out = (float*)d_out;
    float* out_recs = out;                       // [50][16][256]
    float* out_outs = out + 50 * 16 * 256;       // [50][16][1][64][64]

    k_transpose<<<784, 256, 0, stream>>>(wout);
    for (int kw = 0; kw < 54; kw++) {
        k_wave<<<2856, 256, 0, stream>>>(kw, x, osc, w1, b1, w2, b2, win, bin,
                                         wrec, brec, bout, wd2, bd2, wrc, brc,
                                         out_recs, out_outs);
    }
}

// Round 31
// 5589.542 us; speedup vs baseline: 1.0737x; 1.0737x over previous
//
#include <hip/hip_runtime.h>

#define BETA_F 0.9048374180359595f   // fp32 nearest of exp(-0.1)

constexpr int B_ = 16, C1_ = 16, C2_ = 16;
constexpr int S1 = 60, S2 = 56;
constexpr int NCONV2 = C2_ * S2 * S2;   // 50176
constexpr int NREC = 256;

// ---- persistent state (t-parity double buffers) ----
__device__ float g_mem_c1x[2 * 921600];
__device__ float g_mem_c2[802816];
__device__ float g_mem_rec[4096];
__device__ float g_mem_d2[921600];
__device__ float g_mem_rc[65536];
__device__ unsigned char g_spk2bx[2][B_ * NCONV2];
__device__ float g_currx[2][B_ * NCONV2];
__device__ float g_spkd2x[2][921600];
__device__ float g_spkrec2[2 * 4096];
__device__ float g_woutT[NREC * NCONV2];

// LIF subtract-reset, fp32, unfused mul-then-add (order frozen since r13)
__device__ __forceinline__ float lif_sub(float mp, float inp, float& mn_out) {
    float rst = mp > 1.f ? 1.f : 0.f;
    float base = __fadd_rn(__fmul_rn(BETA_F, mp), inp);
    float mn = __fsub_rn(base, rst);
    mn_out = mn;
    return mn > 1.f ? 1.f : 0.f;
}

// ---------------- Wout transpose (bit-copy; once per launch) ----------------
__global__ void k_transpose(const float* __restrict__ Wout) {
    __shared__ float T[64][65];
    int m0 = blockIdx.x * 64;
    for (int k0 = 0; k0 < 256; k0 += 64) {
        __syncthreads();
        for (int e = threadIdx.x; e < 64 * 64; e += 256) {
            int i = e >> 6, k = e & 63;
            T[i][k] = Wout[(size_t)(m0 + i) * 256 + k0 + k];
        }
        __syncthreads();
        for (int e = threadIdx.x; e < 64 * 64; e += 256) {
            int k = e >> 6, i = e & 63;
            g_woutT[(size_t)(k0 + k) * NCONV2 + m0 + i] = T[i][k];
        }
    }
}

// =============== wavefront kernel: 5 layer-instances, disjoint block ranges ==
// [0,448): conv12@k | [448,1472): ffinrec@k-1 | [1472,1864): ffout@k-2
// [1864,2344): deconv2@k-3 | [2344,2856): recon@k-4
__global__ __launch_bounds__(256)
void k_wave(int kw,
            const float* __restrict__ x, const float* __restrict__ osc,
            const float* __restrict__ w1, const float* __restrict__ b1,
            const float* __restrict__ w2, const float* __restrict__ b2,
            const float* __restrict__ win, const float* __restrict__ bin,
            const float* __restrict__ wrec, const float* __restrict__ brec,
            const float* __restrict__ bout,
            const float* __restrict__ wd2, const float* __restrict__ bd2,
            const float* __restrict__ wrc, const float* __restrict__ brc,
            float* __restrict__ out_recs, float* __restrict__ out_outs) {
    __shared__ float smem[8192];           // 32768 B union -> 5 blocks/CU
    const int r = blockIdx.x;
    const int tid = threadIdx.x;

    if (r < 448) {
        // ------- A: conv12 @ t = kw (4-row tiles; s1 split into 2 ci-groups) --
        int t = kw;
        if (t > 49) return;
        int first = (t == 0) ? 1 : 0;
        float* xw = smem;                  // 12*64 = 768
        float* s1g = smem + 768;           // 8*8*60 = 3840 (one ci-group)
        int tile = r % 14, b = (r / 14) & 15, half = r / 224;
        int y0 = 4 * tile;                 // window rows [y0, y0+8)
        int y1 = (tile == 13) ? 60 : (y0 + 4);
        const float* xin = x + ((size_t)t * B_ + b) * 4096;
        for (int e = tid; e < 12 * 64; e += 256)
            xw[e] = xin[(y0 + (e >> 6)) * 64 + (e & 63)];
        __syncthreads();

        int par = t & 1;
        float* mc1_new = g_mem_c1x + (size_t)par * 921600;
        const float* mc1_old = g_mem_c1x + (size_t)(1 - par) * 921600;
        unsigned char* spk2b = g_spk2bx[par];
        float osct = osc[t];
        int c2lo = half * 8;
        int p = tile * 224 + tid;          // valid when tid < 224
        int yy = p / 56, xx = p % 56;
        float acc[8];
#pragma unroll
        for (int u = 0; u < 8; u++) acc[u] = 0.f;

#pragma unroll 1
        for (int cg = 0; cg < 2; cg++) {
            // conv1 for ci-group [cg*8, cg*8+8)
#pragma unroll 1
            for (int cl = 0; cl < 8; cl++) {
                int c = cg * 8 + cl;
                const float* wc = w1 + c * 25;
                float bc = b1[c];
                for (int e = tid; e < 8 * 60; e += 256) {
                    int rr = e / 60, col = e % 60;
                    float s = 0.f;
#pragma unroll
                    for (int ky = 0; ky < 5; ky++)
#pragma unroll
                        for (int kx = 0; kx < 5; kx++)
                            s = fmaf(xw[(rr + ky) * 64 + col + kx], wc[ky * 5 + kx], s);
                    float inp = __fadd_rn(__fadd_rn(s, bc), osct);
                    int gr = y0 + rr;
                    int gidx = ((b * 16 + c) * 60 + gr) * 60 + col;
                    float mp = first ? 0.f : mc1_old[gidx];
                    float mn;
                    float spk = lif_sub(mp, inp, mn);
                    if (half == 0 && gr < y1) mc1_new[gidx] = mn;
                    s1g[cl * 480 + e] = spk;
                }
            }
            __syncthreads();
            // conv2 partial accumulation over this ci-group (ci ascending)
            if (tid < 224) {
#pragma unroll 1
                for (int cl = 0; cl < 8; cl++) {
                    int ci = cg * 8 + cl;
                    const float* ip = s1g + cl * 480 + (yy - y0) * 60 + xx;
                    float ipv[25];
#pragma unroll
                    for (int ky = 0; ky < 5; ky++)
#pragma unroll
                        for (int kx = 0; kx < 5; kx++)
                            ipv[ky * 5 + kx] = ip[ky * 60 + kx];
#pragma unroll
                    for (int u = 0; u < 8; u++) {
                        const float* wp = w2 + (c2lo + u) * 400 + ci * 25;
                        float s = acc[u];
#pragma unroll
                        for (int k = 0; k < 25; k++)
                            s = fmaf(ipv[k], wp[k], s);
                        acc[u] = s;
                    }
                }
            }
            __syncthreads();
        }
        if (tid >= 224) return;
#pragma unroll 1
        for (int u = 0; u < 8; u++) {
            int c2 = c2lo + u;
            float inp = __fadd_rn(__fadd_rn(acc[u], b2[c2]), osct);
            int idx = (b * 16 + c2) * 3136 + p;
            float mp = first ? 0.f : g_mem_c2[idx];
            float mn;
            float spk = lif_sub(mp, inp, mn);
            g_mem_c2[idx] = mn;
            spk2b[idx] = (unsigned char)(spk > 0.5f ? 1 : 0);
        }
    } else if (r < 1472) {
        // ---------------- B: ffinrec @ t = kw-1 (r29 body) ----------------
        int t = kw - 1;
        if (t < 0 || t > 49) return;
        int first = (t == 0) ? 1 : 0;
        float* red = smem;                 // 256
        float* sprev = smem + 256;         // 1024
        float* cur = smem + 1280;          // 4
        int bid = r - 448;
        int n = ((bid >> 5) << 3) + (bid & 7);
        int bg = ((bid >> 3) & 3) * 4;
        int par = t & 1;
        const float* sp_old = g_spkrec2 + (size_t)(1 - par) * 4096;
#pragma unroll
        for (int l = 0; l < 4; l++) {
            int e = tid + l * 256;
            sprev[e] = first ? 0.f : sp_old[(bg + (e >> 8)) * 256 + (e & 255)];
        }
        const unsigned char* sbase = g_spk2bx[par];
        const float* wrow = win + (size_t)n * NCONV2;
        const unsigned char* s0 = sbase + (size_t)(bg + 0) * NCONV2;
        const unsigned char* s1p = sbase + (size_t)(bg + 1) * NCONV2;
        const unsigned char* s2 = sbase + (size_t)(bg + 2) * NCONV2;
        const unsigned char* s3 = sbase + (size_t)(bg + 3) * NCONV2;
        float a0 = 0.f, a1 = 0.f, a2 = 0.f, a3 = 0.f;
        for (int j = 0; j < 49; j++) {     // 49 x 4: strictly k-ascending per acc
            int k = tid + j * 1024;
            float w0 = wrow[k];
            float wA = wrow[k + 256];
            float wB = wrow[k + 512];
            float wC = wrow[k + 768];
            unsigned char p00 = s0[k],       p01 = s1p[k],       p02 = s2[k],       p03 = s3[k];
            unsigned char p10 = s0[k + 256], p11 = s1p[k + 256], p12 = s2[k + 256], p13 = s3[k + 256];
            unsigned char p20 = s0[k + 512], p21 = s1p[k + 512], p22 = s2[k + 512], p23 = s3[k + 512];
            unsigned char p30 = s0[k + 768], p31 = s1p[k + 768], p32 = s2[k + 768], p33 = s3[k + 768];
            a0 = fmaf((float)p00, w0, a0); a1 = fmaf((float)p01, w0, a1);
            a2 = fmaf((float)p02, w0, a2); a3 = fmaf((float)p03, w0, a3);
            a0 = fmaf((float)p10, wA, a0); a1 = fmaf((float)p11, wA, a1);
            a2 = fmaf((float)p12, wA, a2); a3 = fmaf((float)p13, wA, a3);
            a0 = fmaf((float)p20, wB, a0); a1 = fmaf((float)p21, wB, a1);
            a2 = fmaf((float)p22, wB, a2); a3 = fmaf((float)p23, wB, a3);
            a0 = fmaf((float)p30, wC, a0); a1 = fmaf((float)p31, wC, a1);
            a2 = fmaf((float)p32, wC, a2); a3 = fmaf((float)p33, wC, a3);
        }
        float accs[4] = {a0, a1, a2, a3};
#pragma unroll
        for (int u = 0; u < 4; u++) {
            red[tid] = accs[u];
            __syncthreads();
            for (int st = 128; st > 0; st >>= 1) {   // frozen tree
                if (tid < st) red[tid] = __fadd_rn(red[tid], red[tid + st]);
                __syncthreads();
            }
            if (tid == 0) cur[u] = red[0];
            __syncthreads();
        }
        if (tid < 4) {
            int bb = bg + tid;
            const float* wr = wrec + (size_t)n * 256;
            float acc = 0.f;
            for (int k = 0; k < 256; k++) acc = fmaf(sprev[tid * 256 + k], wr[k], acc);
            float cin = __fadd_rn(cur[tid], bin[n]);
            float crc = __fadd_rn(acc, brec[n]);
            float inp = __fadd_rn(__fadd_rn(cin, crc), osc[t]);
            int idx = bb * 256 + n;
            float mp = first ? 0.f : g_mem_rec[idx];
            float rst = mp > 1.f ? 1.f : 0.f;
            float base = __fadd_rn(__fmul_rn(BETA_F, mp), inp);
            float mn = (rst > 0.f) ? 0.f : base;
            g_mem_rec[idx] = mn;
            float spk = mn > 1.f ? 1.f : 0.f;
            g_spkrec2[(size_t)par * 4096 + idx] = spk;
            out_recs[(size_t)t * 4096 + idx] = spk;
        }
    } else if (r < 1864) {
        // ---------------- C: ffout @ t = kw-2 ----------------
        int t = kw - 2;
        if (t < 0 || t > 49) return;
        float* S = smem;                   // [8][256]
        int r2 = r - 1472;
        int mblk = r2 % 196;
        int bhalf = (r2 / 196) * 8;
        int par = t & 1;
#pragma unroll
        for (int l = 0; l < 8; l++) {
            int e = tid + l * 256;
            S[(e >> 8) * 256 + (e & 255)] =
                g_spkrec2[(size_t)par * 4096 + (bhalf + (e >> 8)) * 256 + (e & 255)];
        }
        __syncthreads();
        int m = mblk * 256 + tid;
        float* currw = g_currx[par];
        float acc[8];
#pragma unroll
        for (int b = 0; b < 8; b++) acc[b] = 0.f;
#pragma unroll 4
        for (int k = 0; k < 256; k++) {    // frozen k order per output
            float w = g_woutT[(size_t)k * NCONV2 + m];
#pragma unroll
            for (int b = 0; b < 8; b++) acc[b] = fmaf(S[b * 256 + k], w, acc[b]);
        }
        float bb = bout[m];
#pragma unroll
        for (int b = 0; b < 8; b++)
            currw[(size_t)(bhalf + b) * NCONV2 + m] = __fadd_rn(acc[b], bb);
    } else if (r < 2344) {
        // ---------------- D: deconv2 @ t = kw-3 (4-row tiles) ----------------
        int t = kw - 3;
        if (t < 0 || t > 49) return;
        int first = (t == 0) ? 1 : 0;
        float* sd = smem;                  // 16*8*64 = 8192
        int r3 = r - 1864;
        int tile = r3 % 15, b = (r3 / 15) & 15, half = r3 / 240;
        int r0 = 4 * tile;                 // output rows [r0, r0+4)
        int y0p = r0 - 4;
        int par = t & 1;
        const float* in = g_currx[par] + (size_t)b * NCONV2;
        for (int e = tid; e < 16 * 8 * 64; e += 256) {
            int ci = e / 512;
            int rem = e - ci * 512;
            int rr = rem >> 6, j = rem & 63;
            int iy = y0p + rr;
            int ix = j - 4;
            float v = (iy >= 0 && iy < 56 && ix >= 0 && ix < 56)
                        ? in[ci * 3136 + iy * 56 + ix] : 0.f;
            sd[e] = v;
        }
        __syncthreads();
        if (tid >= 240) return;
        int p = r0 * 60 + tid;             // 4 rows x 60
        int yy = p / 60, xx = p % 60;
        int colo = half * 8;
        float acc[8];
#pragma unroll
        for (int u = 0; u < 8; u++) acc[u] = 0.f;
#pragma unroll
        for (int kp = 0; kp < 5; kp++) {
            int rr = yy - r0 + kp;
#pragma unroll 1
            for (int ci = 0; ci < 16; ci++) {
                const float* ip = sd + ci * 512 + rr * 64 + xx;
                float ipv[5];
#pragma unroll
                for (int kq = 0; kq < 5; kq++) ipv[kq] = ip[kq];
#pragma unroll
                for (int u = 0; u < 8; u++) {
                    const float* wp = wd2 + (ci * 16 + colo + u) * 25 + (4 - kp) * 5;
                    float s = acc[u];
#pragma unroll
                    for (int kq = 0; kq < 5; kq++)
                        s = fmaf(ipv[kq], wp[4 - kq], s);
                    acc[u] = s;
                }
            }
        }
        float osct = osc[t];
        float* spkd2w = g_spkd2x[par];
#pragma unroll 1
        for (int u = 0; u < 8; u++) {
            int co = colo + u;
            float inp = __fadd_rn(__fadd_rn(acc[u], bd2[co]), osct);
            int idx = (b * 16 + co) * 3600 + p;
            float mp = first ? 0.f : g_mem_d2[idx];
            float mn;
            float spk = lif_sub(mp, inp, mn);
            g_mem_d2[idx] = mn;
            spkd2w[idx] = spk;
        }
    } else {
        // ---------------- E: recon @ t = kw-4 (2-row tiles; r30-validated) ----
        int t = kw - 4;
        if (t < 0 || t > 49) return;
        int first = (t == 0) ? 1 : 0;
        float* sd = smem;                  // 16*6*68 = 6528
        int r4 = r - 2344;
        int tile = r4 & 31, b = r4 >> 5;
        int yymin = tile * 2;
        int y0p = yymin - 4;
        int par = t & 1;
        const float* in = g_spkd2x[par] + (size_t)b * 16 * 3600;
        for (int e = tid; e < 16 * 6 * 68; e += 256) {
            int ci = e / 408;
            int rem = e - ci * 408;
            int rr = rem / 68, j = rem - rr * 68;
            int iy = y0p + rr;
            int ix = j - 4;
            float v = (iy >= 0 && iy < 60 && ix >= 0 && ix < 60)
                        ? in[ci * 3600 + iy * 60 + ix] : 0.f;
            sd[e] = v;
        }
        __syncthreads();
        if (tid >= 128) return;
        int p = yymin * 64 + tid;          // 2 rows x 64
        int yy = p >> 6, xx = p & 63;
        float s = 0.f;
#pragma unroll
        for (int kp = 0; kp < 5; kp++) {
            int rr = yy - yymin + kp;
#pragma unroll 1
            for (int ci = 0; ci < 16; ci++) {
                const float* ip = sd + ci * 408 + rr * 68 + xx;
                const float* wp = wrc + ci * 25 + (4 - kp) * 5;   // uniform -> s_load
#pragma unroll
                for (int kq = 0; kq < 5; kq++)
                    s = fmaf(ip[kq], wp[4 - kq], s);
            }
        }
        float inp = __fadd_rn(__fadd_rn(s, brc[0]), osc[t]);
        int idx = b * 4096 + p;
        float mp = first ? 0.f : g_mem_rc[idx];
        float mn;
        float spk = lif_sub(mp, inp, mn);
        g_mem_rc[idx] = mn;
        out_outs[(size_t)t * B_ * 4096 + idx] = spk;
    }
}

extern "C" void kernel_launch(void* const* d_in, const int* in_sizes, int n_in,
                              void* d_out, int out_size, void* d_ws, size_t ws_size,
                              hipStream_t stream) {
    const float* x    = (const float*)d_in[0];
    const float* osc  = (const float*)d_in[1];
    const float* w1   = (const float*)d_in[2];
    const float* b1   = (const float*)d_in[3];
    const float* w2   = (const float*)d_in[4];
    const float* b2   = (const float*)d_in[5];
    const float* win  = (const float*)d_in[6];
    const float* bin  = (const float*)d_in[7];
    const float* wrec = (const float*)d_in[8];
    const float* brec = (const float*)d_in[9];
    const float* wout = (const float*)d_in[10];
    const float* bout = (const float*)d_in[11];
    const float* wd2  = (const float*)d_in[12];
    const float* bd2  = (const float*)d_in[13];
    const float* wrc  = (const float*)d_in[14];
    const float* brc  = (const float*)d_in[15];

    float* out = (float*)d_out;
    float* out_recs = out;                       // [50][16][256]
    float* out_outs = out + 50 * 16 * 256;       // [50][16][1][64][64]

    k_transpose<<<784, 256, 0, stream>>>(wout);
    for (int kw = 0; kw < 54; kw++) {
        k_wave<<<2856, 256, 0, stream>>>(kw, x, osc, w1, b1, w2, b2, win, bin,
                                         wrec, brec, bout, wd2, bd2, wrc, brc,
                                         out_recs, out_outs);
    }
}

// Round 32
// 4860.648 us; speedup vs baseline: 1.2347x; 1.1500x over previous
//
#include <hip/hip_runtime.h>

#define BETA_F 0.9048374180359595f   // fp32 nearest of exp(-0.1)

constexpr int B_ = 16, C1_ = 16, C2_ = 16;
constexpr int S1 = 60, S2 = 56;
constexpr int NCONV2 = C2_ * S2 * S2;   // 50176
constexpr int NREC = 256;

// ---- persistent state (t-parity double buffers) ----
__device__ float g_mem_c1x[2 * 921600];
__device__ float g_mem_c2[802816];
__device__ float g_mem_rec[4096];
__device__ float g_mem_d2[921600];
__device__ float g_mem_rc[65536];
__device__ unsigned char g_spk2bx[2][B_ * NCONV2];
__device__ float g_currx[2][B_ * NCONV2];
__device__ float g_spkd2x[2][921600];
__device__ float g_spkrec2[2 * 4096];
__device__ float g_woutT[NREC * NCONV2];

// LIF subtract-reset, fp32, unfused mul-then-add (order frozen since r13)
__device__ __forceinline__ float lif_sub(float mp, float inp, float& mn_out) {
    float rst = mp > 1.f ? 1.f : 0.f;
    float base = __fadd_rn(__fmul_rn(BETA_F, mp), inp);
    float mn = __fsub_rn(base, rst);
    mn_out = mn;
    return mn > 1.f ? 1.f : 0.f;
}

// ---------------- Wout transpose (bit-copy; once per launch) ----------------
__global__ void k_transpose(const float* __restrict__ Wout) {
    __shared__ float T[64][65];
    int m0 = blockIdx.x * 64;
    for (int k0 = 0; k0 < 256; k0 += 64) {
        __syncthreads();
        for (int e = threadIdx.x; e < 64 * 64; e += 256) {
            int i = e >> 6, k = e & 63;
            T[i][k] = Wout[(size_t)(m0 + i) * 256 + k0 + k];
        }
        __syncthreads();
        for (int e = threadIdx.x; e < 64 * 64; e += 256) {
            int k = e >> 6, i = e & 63;
            g_woutT[(size_t)(k0 + k) * NCONV2 + m0 + i] = T[i][k];
        }
    }
}

// =============== wavefront kernel: 5 layer-instances, disjoint block ranges ==
// [0,448): conv12@k | [448,1472): ffinrec@k-1 | [1472,1864): ffout@k-2
// [1864,2824): deconv2@k-3 (2-row tiles) | [2824,3336): recon@k-4
__global__ __launch_bounds__(256)
void k_wave(int kw,
            const float* __restrict__ x, const float* __restrict__ osc,
            const float* __restrict__ w1, const float* __restrict__ b1,
            const float* __restrict__ w2, const float* __restrict__ b2,
            const float* __restrict__ win, const float* __restrict__ bin,
            const float* __restrict__ wrec, const float* __restrict__ brec,
            const float* __restrict__ bout,
            const float* __restrict__ wd2, const float* __restrict__ bd2,
            const float* __restrict__ wrc, const float* __restrict__ brc,
            float* __restrict__ out_recs, float* __restrict__ out_outs) {
    __shared__ float smem[6528];           // 26112 B union -> 6 blocks/CU
    const int r = blockIdx.x;
    const int tid = threadIdx.x;

    if (r < 448) {
        // ------- A: conv12 @ t = kw (4-row tiles; s1 split into 2 ci-groups) --
        int t = kw;
        if (t > 49) return;
        int first = (t == 0) ? 1 : 0;
        float* xw = smem;                  // 12*64 = 768
        float* s1g = smem + 768;           // 8*8*60 = 3840 (one ci-group)
        int tile = r % 14, b = (r / 14) & 15, half = r / 224;
        int y0 = 4 * tile;                 // window rows [y0, y0+8)
        int y1 = (tile == 13) ? 60 : (y0 + 4);
        const float* xin = x + ((size_t)t * B_ + b) * 4096;
        for (int e = tid; e < 12 * 64; e += 256)
            xw[e] = xin[(y0 + (e >> 6)) * 64 + (e & 63)];
        __syncthreads();

        int par = t & 1;
        float* mc1_new = g_mem_c1x + (size_t)par * 921600;
        const float* mc1_old = g_mem_c1x + (size_t)(1 - par) * 921600;
        unsigned char* spk2b = g_spk2bx[par];
        float osct = osc[t];
        int c2lo = half * 8;
        int p = tile * 224 + tid;          // valid when tid < 224
        int yy = p / 56, xx = p % 56;
        float acc[8];
#pragma unroll
        for (int u = 0; u < 8; u++) acc[u] = 0.f;

#pragma unroll 1
        for (int cg = 0; cg < 2; cg++) {
#pragma unroll 1
            for (int cl = 0; cl < 8; cl++) {
                int c = cg * 8 + cl;
                const float* wc = w1 + c * 25;
                float bc = b1[c];
                for (int e = tid; e < 8 * 60; e += 256) {
                    int rr = e / 60, col = e % 60;
                    float s = 0.f;
#pragma unroll
                    for (int ky = 0; ky < 5; ky++)
#pragma unroll
                        for (int kx = 0; kx < 5; kx++)
                            s = fmaf(xw[(rr + ky) * 64 + col + kx], wc[ky * 5 + kx], s);
                    float inp = __fadd_rn(__fadd_rn(s, bc), osct);
                    int gr = y0 + rr;
                    int gidx = ((b * 16 + c) * 60 + gr) * 60 + col;
                    float mp = first ? 0.f : mc1_old[gidx];
                    float mn;
                    float spk = lif_sub(mp, inp, mn);
                    if (half == 0 && gr < y1) mc1_new[gidx] = mn;
                    s1g[cl * 480 + e] = spk;
                }
            }
            __syncthreads();
            if (tid < 224) {
#pragma unroll 1
                for (int cl = 0; cl < 8; cl++) {
                    int ci = cg * 8 + cl;
                    const float* ip = s1g + cl * 480 + (yy - y0) * 60 + xx;
                    float ipv[25];
#pragma unroll
                    for (int ky = 0; ky < 5; ky++)
#pragma unroll
                        for (int kx = 0; kx < 5; kx++)
                            ipv[ky * 5 + kx] = ip[ky * 60 + kx];
#pragma unroll
                    for (int u = 0; u < 8; u++) {
                        const float* wp = w2 + (c2lo + u) * 400 + ci * 25;
                        float s = acc[u];
#pragma unroll
                        for (int k = 0; k < 25; k++)
                            s = fmaf(ipv[k], wp[k], s);
                        acc[u] = s;
                    }
                }
            }
            __syncthreads();
        }
        if (tid >= 224) return;
#pragma unroll 1
        for (int u = 0; u < 8; u++) {
            int c2 = c2lo + u;
            float inp = __fadd_rn(__fadd_rn(acc[u], b2[c2]), osct);
            int idx = (b * 16 + c2) * 3136 + p;
            float mp = first ? 0.f : g_mem_c2[idx];
            float mn;
            float spk = lif_sub(mp, inp, mn);
            g_mem_c2[idx] = mn;
            spk2b[idx] = (unsigned char)(spk > 0.5f ? 1 : 0);
        }
    } else if (r < 1472) {
        // ---------------- B: ffinrec @ t = kw-1 (r29 body) ----------------
        int t = kw - 1;
        if (t < 0 || t > 49) return;
        int first = (t == 0) ? 1 : 0;
        float* red = smem;                 // 256
        float* sprev = smem + 256;         // 1024
        float* cur = smem + 1280;          // 4
        int bid = r - 448;
        int n = ((bid >> 5) << 3) + (bid & 7);
        int bg = ((bid >> 3) & 3) * 4;
        int par = t & 1;
        const float* sp_old = g_spkrec2 + (size_t)(1 - par) * 4096;
#pragma unroll
        for (int l = 0; l < 4; l++) {
            int e = tid + l * 256;
            sprev[e] = first ? 0.f : sp_old[(bg + (e >> 8)) * 256 + (e & 255)];
        }
        const unsigned char* sbase = g_spk2bx[par];
        const float* wrow = win + (size_t)n * NCONV2;
        const unsigned char* s0 = sbase + (size_t)(bg + 0) * NCONV2;
        const unsigned char* s1p = sbase + (size_t)(bg + 1) * NCONV2;
        const unsigned char* s2 = sbase + (size_t)(bg + 2) * NCONV2;
        const unsigned char* s3 = sbase + (size_t)(bg + 3) * NCONV2;
        float a0 = 0.f, a1 = 0.f, a2 = 0.f, a3 = 0.f;
        for (int j = 0; j < 49; j++) {     // 49 x 4: strictly k-ascending per acc
            int k = tid + j * 1024;
            float w0 = wrow[k];
            float wA = wrow[k + 256];
            float wB = wrow[k + 512];
            float wC = wrow[k + 768];
            unsigned char p00 = s0[k],       p01 = s1p[k],       p02 = s2[k],       p03 = s3[k];
            unsigned char p10 = s0[k + 256], p11 = s1p[k + 256], p12 = s2[k + 256], p13 = s3[k + 256];
            unsigned char p20 = s0[k + 512], p21 = s1p[k + 512], p22 = s2[k + 512], p23 = s3[k + 512];
            unsigned char p30 = s0[k + 768], p31 = s1p[k + 768], p32 = s2[k + 768], p33 = s3[k + 768];
            a0 = fmaf((float)p00, w0, a0); a1 = fmaf((float)p01, w0, a1);
            a2 = fmaf((float)p02, w0, a2); a3 = fmaf((float)p03, w0, a3);
            a0 = fmaf((float)p10, wA, a0); a1 = fmaf((float)p11, wA, a1);
            a2 = fmaf((float)p12, wA, a2); a3 = fmaf((float)p13, wA, a3);
            a0 = fmaf((float)p20, wB, a0); a1 = fmaf((float)p21, wB, a1);
            a2 = fmaf((float)p22, wB, a2); a3 = fmaf((float)p23, wB, a3);
            a0 = fmaf((float)p30, wC, a0); a1 = fmaf((float)p31, wC, a1);
            a2 = fmaf((float)p32, wC, a2); a3 = fmaf((float)p33, wC, a3);
        }
        float accs[4] = {a0, a1, a2, a3};
#pragma unroll
        for (int u = 0; u < 4; u++) {
            red[tid] = accs[u];
            __syncthreads();
            for (int st = 128; st > 0; st >>= 1) {   // frozen tree
                if (tid < st) red[tid] = __fadd_rn(red[tid], red[tid + st]);
                __syncthreads();
            }
            if (tid == 0) cur[u] = red[0];
            __syncthreads();
        }
        if (tid < 4) {
            int bb = bg + tid;
            const float* wr = wrec + (size_t)n * 256;
            float acc = 0.f;
            for (int k = 0; k < 256; k++) acc = fmaf(sprev[tid * 256 + k], wr[k], acc);
            float cin = __fadd_rn(cur[tid], bin[n]);
            float crc = __fadd_rn(acc, brec[n]);
            float inp = __fadd_rn(__fadd_rn(cin, crc), osc[t]);
            int idx = bb * 256 + n;
            float mp = first ? 0.f : g_mem_rec[idx];
            float rst = mp > 1.f ? 1.f : 0.f;
            float base = __fadd_rn(__fmul_rn(BETA_F, mp), inp);
            float mn = (rst > 0.f) ? 0.f : base;
            g_mem_rec[idx] = mn;
            float spk = mn > 1.f ? 1.f : 0.f;
            g_spkrec2[(size_t)par * 4096 + idx] = spk;
            out_recs[(size_t)t * 4096 + idx] = spk;
        }
    } else if (r < 1864) {
        // ---------------- C: ffout @ t = kw-2 ----------------
        int t = kw - 2;
        if (t < 0 || t > 49) return;
        float* S = smem;                   // [8][256]
        int r2 = r - 1472;
        int mblk = r2 % 196;
        int bhalf = (r2 / 196) * 8;
        int par = t & 1;
#pragma unroll
        for (int l = 0; l < 8; l++) {
            int e = tid + l * 256;
            S[(e >> 8) * 256 + (e & 255)] =
                g_spkrec2[(size_t)par * 4096 + (bhalf + (e >> 8)) * 256 + (e & 255)];
        }
        __syncthreads();
        int m = mblk * 256 + tid;
        float* currw = g_currx[par];
        float acc[8];
#pragma unroll
        for (int b = 0; b < 8; b++) acc[b] = 0.f;
#pragma unroll 4
        for (int k = 0; k < 256; k++) {    // frozen k order per output
            float w = g_woutT[(size_t)k * NCONV2 + m];
#pragma unroll
            for (int b = 0; b < 8; b++) acc[b] = fmaf(S[b * 256 + k], w, acc[b]);
        }
        float bb = bout[m];
#pragma unroll
        for (int b = 0; b < 8; b++)
            currw[(size_t)(bhalf + b) * NCONV2 + m] = __fadd_rn(acc[b], bb);
    } else if (r < 2824) {
        // ---------------- D: deconv2 @ t = kw-3 (2-row tiles) ----------------
        int t = kw - 3;
        if (t < 0 || t > 49) return;
        int first = (t == 0) ? 1 : 0;
        float* sd = smem;                  // 16*6*64 = 6144
        int r3 = r - 1864;
        int tile = r3 % 30, b = (r3 / 30) & 15, half = r3 / 480;
        int r0 = 2 * tile;                 // output rows [r0, r0+2)
        int y0p = r0 - 4;                  // padded window start (6 rows)
        int par = t & 1;
        const float* in = g_currx[par] + (size_t)b * NCONV2;
        for (int e = tid; e < 16 * 6 * 64; e += 256) {
            int ci = e / 384;
            int rem = e - ci * 384;
            int rr = rem >> 6, j = rem & 63;
            int iy = y0p + rr;
            int ix = j - 4;
            float v = (iy >= 0 && iy < 56 && ix >= 0 && ix < 56)
                        ? in[ci * 3136 + iy * 56 + ix] : 0.f;
            sd[e] = v;
        }
        __syncthreads();
        if (tid >= 120) return;
        int p = r0 * 60 + tid;             // 2 rows x 60
        int yy = p / 60, xx = p % 60;
        int colo = half * 8;
        float acc[8];
#pragma unroll
        for (int u = 0; u < 8; u++) acc[u] = 0.f;
#pragma unroll
        for (int kp = 0; kp < 5; kp++) {
            int rr = yy - r0 + kp;         // 0..5 within 6-row window
#pragma unroll 1
            for (int ci = 0; ci < 16; ci++) {
                const float* ip = sd + ci * 384 + rr * 64 + xx;
                float ipv[5];
#pragma unroll
                for (int kq = 0; kq < 5; kq++) ipv[kq] = ip[kq];
#pragma unroll
                for (int u = 0; u < 8; u++) {
                    const float* wp = wd2 + (ci * 16 + colo + u) * 25 + (4 - kp) * 5;
                    float s = acc[u];
#pragma unroll
                    for (int kq = 0; kq < 5; kq++)
                        s = fmaf(ipv[kq], wp[4 - kq], s);
                    acc[u] = s;
                }
            }
        }
        float osct = osc[t];
        float* spkd2w = g_spkd2x[par];
#pragma unroll 1
        for (int u = 0; u < 8; u++) {
            int co = colo + u;
            float inp = __fadd_rn(__fadd_rn(acc[u], bd2[co]), osct);
            int idx = (b * 16 + co) * 3600 + p;
            float mp = first ? 0.f : g_mem_d2[idx];
            float mn;
            float spk = lif_sub(mp, inp, mn);
            g_mem_d2[idx] = mn;
            spkd2w[idx] = spk;
        }
    } else {
        // ---------------- E: recon @ t = kw-4 (2-row tiles) ----------------
        int t = kw - 4;
        if (t < 0 || t > 49) return;
        int first = (t == 0) ? 1 : 0;
        float* sd = smem;                  // 16*6*68 = 6528
        int r4 = r - 2824;
        int tile = r4 & 31, b = r4 >> 5;
        int yymin = tile * 2;
        int y0p = yymin - 4;
        int par = t & 1;
        const float* in = g_spkd2x[par] + (size_t)b * 16 * 3600;
        for (int e = tid; e < 16 * 6 * 68; e += 256) {
            int ci = e / 408;
            int rem = e - ci * 408;
            int rr = rem / 68, j = rem - rr * 68;
            int iy = y0p + rr;
            int ix = j - 4;
            float v = (iy >= 0 && iy < 60 && ix >= 0 && ix < 60)
                        ? in[ci * 3600 + iy * 60 + ix] : 0.f;
            sd[e] = v;
        }
        __syncthreads();
        if (tid >= 128) return;
        int p = yymin * 64 + tid;          // 2 rows x 64
        int yy = p >> 6, xx = p & 63;
        float s = 0.f;
#pragma unroll
        for (int kp = 0; kp < 5; kp++) {
            int rr = yy - yymin + kp;
#pragma unroll 1
            for (int ci = 0; ci < 16; ci++) {
                const float* ip = sd + ci * 408 + rr * 68 + xx;
                const float* wp = wrc + ci * 25 + (4 - kp) * 5;   // uniform -> s_load
#pragma unroll
                for (int kq = 0; kq < 5; kq++)
                    s = fmaf(ip[kq], wp[4 - kq], s);
            }
        }
        float inp = __fadd_rn(__fadd_rn(s, brc[0]), osc[t]);
        int idx = b * 4096 + p;
        float mp = first ? 0.f : g_mem_rc[idx];
        float mn;
        float spk = lif_sub(mp, inp, mn);
        g_mem_rc[idx] = mn;
        out_outs[(size_t)t * B_ * 4096 + idx] = spk;
    }
}

extern "C" void kernel_launch(void* const* d_in, const int* in_sizes, int n_in,
                              void* d_out, int out_size, void* d_ws, size_t ws_size,
                              hipStream_t stream) {
    const float* x    = (const float*)d_in[0];
    const float* osc  = (const float*)d_in[1];
    const float* w1   = (const float*)d_in[2];
    const float* b1   = (const float*)d_in[3];
    const float* w2   = (const float*)d_in[4];
    const float* b2   = (const float*)d_in[5];
    const float* win  = (const float*)d_in[6];
    const float* bin  = (const float*)d_in[7];
    const float* wrec = (const float*)d_in[8];
    const float* brec = (const float*)d_in[9];
    const float* wout = (const float*)d_in[10];
    const float* bout = (const float*)d_in[11];
    const float* wd2  = (const float*)d_in[12];
    const float* bd2  = (const float*)d_in[13];
    const float* wrc  = (const float*)d_in[14];
    const float* brc  = (const float*)d_in[15];

    float* out = (float*)d_out;
    float* out_recs = out;                       // [50][16][256]
    float* out_outs = out + 50 * 16 * 256;       // [50][16][1][64][64]

    k_transpose<<<784, 256, 0, stream>>>(wout);
    for (int kw = 0; kw < 54; kw++) {
        k_wave<<<3336, 256, 0, stream>>>(kw, x, osc, w1, b1, w2, b2, win, bin,
                                         wrec, brec, bout, wd2, bd2, wrc, brc,
                                         out_recs, out_outs);
    }
}